// Round 12
// baseline (404.176 us; speedup 1.0000x reference)
//
#include <hip/hip_runtime.h>
#include <math.h>

typedef unsigned long long u64;
typedef float  f32x4 __attribute__((ext_vector_type(4)));
typedef int    i32x4 __attribute__((ext_vector_type(4)));

#define T_LEN   4096
#define VOCAB   50257
#define TOP_M   4
#define WEIGHT  0.5f
#define HASH_B  1315423911ull

#define MEGA_THREADS  256
#define CHAIN_BLOCKS  16          // 16 * 256 = 4096 = T_LEN
#define COPY_GRID     1264        // 16 + 1264 = 1280 = 5 blocks/CU * 256 CUs (all co-resident)

// ---------------- Mega-kernel: blocks 0..15 = chain, 16..1279 = persistent chunk copy ----
// 32KB static LDS caps residency at 5 blocks/CU (the measured BW knee: 6.06 TB/s
// vs 4.86 at 8/CU, 5.9 at 4/CU). Each copy block owns one contiguous chunk and
// streams it sequentially (4KB per wave-iteration, nt load+store) -> 5 sequential
// address streams per CU, no further block dispatch.
__global__ void __launch_bounds__(MEGA_THREADS) mega_kernel(
        const int* __restrict__ ids,
        const f32x4* __restrict__ src, f32x4* __restrict__ dst,
        size_t n4, size_t chunk,
        int* __restrict__ idxs, float* __restrict__ vals) {
    __shared__ int sids[T_LEN];
    __shared__ int s[T_LEN];

    if (blockIdx.x >= CHAIN_BLOCKS) {
        // ---- copy role: persistent contiguous chunk ----
        size_t cb  = blockIdx.x - CHAIN_BLOCKS;            // 0..COPY_GRID-1
        size_t beg = cb * chunk;
        size_t end = beg + chunk;
        if (end > n4) end = n4;
        for (size_t k = beg + threadIdx.x; k < end; k += MEGA_THREADS) {
            f32x4 v = __builtin_nontemporal_load(&src[k]);
            __builtin_nontemporal_store(v, &dst[k]);
        }
        return;
    }

    // ---- chain role ----
    {
        i32x4* dst4 = (i32x4*)sids;
        const i32x4* g4 = (const i32x4*)ids;
        for (int i = threadIdx.x; i < T_LEN / 4; i += MEGA_THREADS) dst4[i] = g4[i];
    }
    __syncthreads();
    const u64 B1 = HASH_B;
    const u64 B2 = B1 * B1;
    const u64 B3 = B2 * B1;
    for (int i = threadIdx.x; i < T_LEN; i += MEGA_THREADS) {
        if (i < 3) { s[i] = -1; continue; }
        u64 fp = (u64)(unsigned)(sids[i - 3] + 1) * B3
               + (u64)(unsigned)(sids[i - 2] + 1) * B2
               + (u64)(unsigned)(sids[i - 1] + 1) * B1
               + (u64)(unsigned)(sids[i]     + 1);
        s[i] = (int)(fp & 0xFFFFull);
    }
    __syncthreads();

    int t = blockIdx.x * MEGA_THREADS + threadIdx.x;   // 0..4095 exact
    if (t < 3) {
        *(i32x4*)&idxs[t * 4] = (i32x4){0, 0, 0, 0};
        *(f32x4*)&vals[t * 4] = (f32x4){0.f, 0.f, 0.f, 0.f};
        return;
    }
    const int mys = s[t];

    // register-resident slot state
    u64 key = 0ull;
    int tk[TOP_M] = {0, 0, 0, 0};
    int cs[TOP_M] = {0, 0, 0, 0};
    bool dead = false;

    const i32x4* s4 = (const i32x4*)s;
    for (int qb = 0; qb < T_LEN / 4; qb += 8) {
        i32x4 v[8];
        #pragma unroll
        for (int u = 0; u < 8; ++u) v[u] = s4[qb + u];     // broadcast ds_read_b128 ×8
        bool any = false;
        #pragma unroll
        for (int u = 0; u < 8; ++u)
            any |= (v[u].x == mys) | (v[u].y == mys) | (v[u].z == mys) | (v[u].w == mys);
        if (!any) continue;

        #pragma unroll
        for (int u = 0; u < 8; ++u) {
            #pragma unroll
            for (int j = 0; j < 4; ++j) {
                int sv = (j == 0) ? v[u].x : (j == 1) ? v[u].y : (j == 2) ? v[u].z : v[u].w;
                if (sv != mys) continue;
                int tp = (qb + u) * 4 + j;
                if (tp < t) { dead = true; continue; }
                if (dead) continue;

                // ---- process chain member at position tp ----
                u64 wk = (u64)(unsigned)(sids[tp - 3] + 1) * B3
                       + (u64)(unsigned)(sids[tp - 2] + 1) * B2
                       + (u64)(unsigned)(sids[tp - 1] + 1) * B1
                       + (u64)(unsigned)(sids[tp]     + 1) + 1ull;
                bool key_match = (key == wk);

                int tot = 0;
                #pragma unroll
                for (int m = 0; m < TOP_M; ++m) tot += (tk[m] > 0) ? cs[m] : 0;
                bool emit = key_match && (tot > 0);
                float denom = fmaxf((float)tot, 1.0f);

                int   oi[TOP_M];
                float ov[TOP_M];
                #pragma unroll
                for (int m = 0; m < TOP_M; ++m) {
                    bool ok = emit && (tk[m] > 0) && (cs[m] > 0);
                    float p = fmaxf(1e-9f, (float)cs[m] / denom);
                    ov[m] = ok ? (logf(p) * WEIGHT) : 0.0f;
                    oi[m] = ok ? (tk[m] - 1) : 0;
                }
                *(i32x4*)&idxs[tp * 4] = (i32x4){oi[0], oi[1], oi[2], oi[3]};
                *(f32x4*)&vals[tp * 4] = (f32x4){ov[0], ov[1], ov[2], ov[3]};

                if (tp < T_LEN - 1) {                      // do_upd = active & has_next
                    if (!key_match) {
                        #pragma unroll
                        for (int m = 0; m < TOP_M; ++m) { tk[m] = 0; cs[m] = 0; }
                    }
                    key = wk;
                    int ntp1 = sids[tp + 1] + 1;

                    int ins = -1;
                    #pragma unroll
                    for (int m = 0; m < TOP_M; ++m) if (ins < 0 && tk[m] == ntp1) ins = m;
                    bool matched = (ins >= 0);
                    if (ins < 0) {
                        #pragma unroll
                        for (int m = 0; m < TOP_M; ++m) if (ins < 0 && tk[m] == 0) ins = m;
                    }
                    if (ins < 0) {
                        int best = cs[0]; ins = 0;
                        #pragma unroll
                        for (int m = 1; m < TOP_M; ++m) if (cs[m] < best) { best = cs[m]; ins = m; }
                    }
                    int cur = 0;
                    #pragma unroll
                    for (int m = 0; m < TOP_M; ++m) if (m == ins) cur = cs[m];
                    int new_cnt = matched ? min(65535, cur + 1) : 1;
                    #pragma unroll
                    for (int m = 0; m < TOP_M; ++m) if (m == ins) { tk[m] = ntp1; cs[m] = new_cnt; }
                }
            }
        }
        if (dead) break;   // not a head: everything after my first earlier twin is irrelevant
    }
}

// ---------------- Scatter: <=4 atomic adds per row, after copy completed ----------------
__global__ void scatter_kernel(const int* __restrict__ idxs,
                               const float* __restrict__ vals,
                               float* __restrict__ out) {
    int i = blockIdx.x * blockDim.x + threadIdx.x;
    if (i >= T_LEN * TOP_M) return;
    float v = vals[i];
    if (v != 0.0f) {
        int t = i / TOP_M;
        atomicAdd(out + (size_t)t * VOCAB + idxs[i], v);
    }
}

extern "C" void kernel_launch(void* const* d_in, const int* in_sizes, int n_in,
                              void* d_out, int out_size, void* d_ws, size_t ws_size,
                              hipStream_t stream) {
    const float* logits = (const float*)d_in[0];
    const int*   ids    = (const int*)d_in[1];
    float*       out    = (float*)d_out;

    char* ws = (char*)d_ws;
    int*   idxs = (int*)(ws);              // 16384*4 = 64 KB
    float* vals = (float*)(ws + 65536);    // 64 KB

    size_t n4 = (size_t)out_size / 4;      // 51,463,168
    size_t chunk = (n4 + COPY_GRID - 1) / COPY_GRID;
    mega_kernel<<<CHAIN_BLOCKS + COPY_GRID, MEGA_THREADS, 0, stream>>>(
        ids, (const f32x4*)logits, (f32x4*)out, n4, chunk, idxs, vals);

    scatter_kernel<<<(T_LEN * TOP_M + 255) / 256, 256, 0, stream>>>(idxs, vals, out);
}

// Round 13
// 289.741 us; speedup vs baseline: 1.3950x; 1.3950x over previous
//
#include <hip/hip_runtime.h>
#include <math.h>

typedef unsigned long long u64;
typedef float  f32x4 __attribute__((ext_vector_type(4)));
typedef int    i32x4 __attribute__((ext_vector_type(4)));

#define T_LEN   4096
#define VOCAB   50257
#define TOP_M   4
#define WEIGHT  0.5f
#define HASH_B  1315423911ull

#define MEGA_THREADS  256
#define CHAIN_BLOCKS  16          // 16 * 256 = 4096 = T_LEN

// ---------------- Mega-kernel: blocks 0..15 = chain, rest = dense nt-copy ----------------
// Chain and copy are data-independent; fusing them into one dispatch hides the
// chain's ~15 us under the 201K copy blocks. The 32KB static LDS (allocated for
// every block) caps residency at 5 blocks/CU — the measured BW knee: 6.06 TB/s
// combined vs 4.86 at 8 blocks/CU (R4) and ~5.9 at 4 blocks/CU (R11). Fewer
// concurrent wave streams per CU -> better DRAM page locality. One-shot flat
// blocks beat persistent chunks (R12: 4.1 TB/s) because the dispatcher's rolling
// window keeps the in-flight address range contiguous.
__global__ void __launch_bounds__(MEGA_THREADS) mega_kernel(
        const int* __restrict__ ids,
        const f32x4* __restrict__ src, f32x4* __restrict__ dst, size_t n4,
        int* __restrict__ idxs, float* __restrict__ vals) {
    __shared__ int sids[T_LEN];
    __shared__ int s[T_LEN];

    if (blockIdx.x >= CHAIN_BLOCKS) {
        // ---- copy role: flat, one float4/thread, nt load + nt store (measured best) ----
        size_t k = (size_t)(blockIdx.x - CHAIN_BLOCKS) * MEGA_THREADS + threadIdx.x;
        if (k < n4) {
            f32x4 v = __builtin_nontemporal_load(&src[k]);
            __builtin_nontemporal_store(v, &dst[k]);
        }
        return;
    }

    // ---- chain role ----
    {
        i32x4* dst4 = (i32x4*)sids;
        const i32x4* g4 = (const i32x4*)ids;
        for (int i = threadIdx.x; i < T_LEN / 4; i += MEGA_THREADS) dst4[i] = g4[i];
    }
    __syncthreads();
    const u64 B1 = HASH_B;
    const u64 B2 = B1 * B1;
    const u64 B3 = B2 * B1;
    for (int i = threadIdx.x; i < T_LEN; i += MEGA_THREADS) {
        if (i < 3) { s[i] = -1; continue; }
        u64 fp = (u64)(unsigned)(sids[i - 3] + 1) * B3
               + (u64)(unsigned)(sids[i - 2] + 1) * B2
               + (u64)(unsigned)(sids[i - 1] + 1) * B1
               + (u64)(unsigned)(sids[i]     + 1);
        s[i] = (int)(fp & 0xFFFFull);
    }
    __syncthreads();

    int t = blockIdx.x * MEGA_THREADS + threadIdx.x;   // 0..4095 exact
    if (t < 3) {
        *(i32x4*)&idxs[t * 4] = (i32x4){0, 0, 0, 0};
        *(f32x4*)&vals[t * 4] = (f32x4){0.f, 0.f, 0.f, 0.f};
        return;
    }
    const int mys = s[t];

    // register-resident slot state
    u64 key = 0ull;
    int tk[TOP_M] = {0, 0, 0, 0};
    int cs[TOP_M] = {0, 0, 0, 0};
    bool dead = false;

    const i32x4* s4 = (const i32x4*)s;
    for (int qb = 0; qb < T_LEN / 4; qb += 8) {
        i32x4 v[8];
        #pragma unroll
        for (int u = 0; u < 8; ++u) v[u] = s4[qb + u];     // broadcast ds_read_b128 ×8
        bool any = false;
        #pragma unroll
        for (int u = 0; u < 8; ++u)
            any |= (v[u].x == mys) | (v[u].y == mys) | (v[u].z == mys) | (v[u].w == mys);
        if (!any) continue;

        #pragma unroll
        for (int u = 0; u < 8; ++u) {
            #pragma unroll
            for (int j = 0; j < 4; ++j) {
                int sv = (j == 0) ? v[u].x : (j == 1) ? v[u].y : (j == 2) ? v[u].z : v[u].w;
                if (sv != mys) continue;
                int tp = (qb + u) * 4 + j;
                if (tp < t) { dead = true; continue; }
                if (dead) continue;

                // ---- process chain member at position tp ----
                u64 wk = (u64)(unsigned)(sids[tp - 3] + 1) * B3
                       + (u64)(unsigned)(sids[tp - 2] + 1) * B2
                       + (u64)(unsigned)(sids[tp - 1] + 1) * B1
                       + (u64)(unsigned)(sids[tp]     + 1) + 1ull;
                bool key_match = (key == wk);

                int tot = 0;
                #pragma unroll
                for (int m = 0; m < TOP_M; ++m) tot += (tk[m] > 0) ? cs[m] : 0;
                bool emit = key_match && (tot > 0);
                float denom = fmaxf((float)tot, 1.0f);

                int   oi[TOP_M];
                float ov[TOP_M];
                #pragma unroll
                for (int m = 0; m < TOP_M; ++m) {
                    bool ok = emit && (tk[m] > 0) && (cs[m] > 0);
                    float p = fmaxf(1e-9f, (float)cs[m] / denom);
                    ov[m] = ok ? (logf(p) * WEIGHT) : 0.0f;
                    oi[m] = ok ? (tk[m] - 1) : 0;
                }
                *(i32x4*)&idxs[tp * 4] = (i32x4){oi[0], oi[1], oi[2], oi[3]};
                *(f32x4*)&vals[tp * 4] = (f32x4){ov[0], ov[1], ov[2], ov[3]};

                if (tp < T_LEN - 1) {                      // do_upd = active & has_next
                    if (!key_match) {
                        #pragma unroll
                        for (int m = 0; m < TOP_M; ++m) { tk[m] = 0; cs[m] = 0; }
                    }
                    key = wk;
                    int ntp1 = sids[tp + 1] + 1;

                    int ins = -1;
                    #pragma unroll
                    for (int m = 0; m < TOP_M; ++m) if (ins < 0 && tk[m] == ntp1) ins = m;
                    bool matched = (ins >= 0);
                    if (ins < 0) {
                        #pragma unroll
                        for (int m = 0; m < TOP_M; ++m) if (ins < 0 && tk[m] == 0) ins = m;
                    }
                    if (ins < 0) {
                        int best = cs[0]; ins = 0;
                        #pragma unroll
                        for (int m = 1; m < TOP_M; ++m) if (cs[m] < best) { best = cs[m]; ins = m; }
                    }
                    int cur = 0;
                    #pragma unroll
                    for (int m = 0; m < TOP_M; ++m) if (m == ins) cur = cs[m];
                    int new_cnt = matched ? min(65535, cur + 1) : 1;
                    #pragma unroll
                    for (int m = 0; m < TOP_M; ++m) if (m == ins) { tk[m] = ntp1; cs[m] = new_cnt; }
                }
            }
        }
        if (dead) break;   // not a head: everything after my first earlier twin is irrelevant
    }
}

// ---------------- Scatter: <=4 atomic adds per row, after copy completed ----------------
__global__ void scatter_kernel(const int* __restrict__ idxs,
                               const float* __restrict__ vals,
                               float* __restrict__ out) {
    int i = blockIdx.x * blockDim.x + threadIdx.x;
    if (i >= T_LEN * TOP_M) return;
    float v = vals[i];
    if (v != 0.0f) {
        int t = i / TOP_M;
        atomicAdd(out + (size_t)t * VOCAB + idxs[i], v);
    }
}

extern "C" void kernel_launch(void* const* d_in, const int* in_sizes, int n_in,
                              void* d_out, int out_size, void* d_ws, size_t ws_size,
                              hipStream_t stream) {
    const float* logits = (const float*)d_in[0];
    const int*   ids    = (const int*)d_in[1];
    float*       out    = (float*)d_out;

    char* ws = (char*)d_ws;
    int*   idxs = (int*)(ws);              // 16384*4 = 64 KB
    float* vals = (float*)(ws + 65536);    // 64 KB

    size_t n4 = (size_t)out_size / 4;      // 51,463,168 = 256 * 201,028 exact
    uint32_t copy_blocks = (uint32_t)((n4 + MEGA_THREADS - 1) / MEGA_THREADS);
    mega_kernel<<<CHAIN_BLOCKS + copy_blocks, MEGA_THREADS, 0, stream>>>(
        ids, (const f32x4*)logits, (f32x4*)out, n4, idxs, vals);

    scatter_kernel<<<(T_LEN * TOP_M + 255) / 256, 256, 0, stream>>>(idxs, vals, out);
}